// Round 1
// baseline (4596.548 us; speedup 1.0000x reference)
//
#include <hip/hip_runtime.h>
#include <string.h>

#define Dims 256
#define BM 32
#define BN 32
#define KC 128

// ---------- Threefry2x32 (JAX), usable host+device ----------
__host__ __device__ inline void tf2x32(unsigned k0, unsigned k1,
                                       unsigned x0, unsigned x1,
                                       unsigned* o0, unsigned* o1) {
  unsigned ks[3] = {k0, k1, k0 ^ k1 ^ 0x1BD11BDAu};
  x0 += ks[0]; x1 += ks[1];
  const unsigned rA[4] = {13u, 15u, 26u, 6u};
  const unsigned rB[4] = {17u, 29u, 16u, 24u};
#pragma unroll
  for (int g = 0; g < 5; ++g) {
    const unsigned* rr = (g & 1) ? rB : rA;
#pragma unroll
    for (int j = 0; j < 4; ++j) {
      x0 += x1;
      x1 = (x1 << rr[j]) | (x1 >> (32u - rr[j]));
      x1 ^= x0;
    }
    x0 += ks[(g + 1) % 3];
    x1 += ks[(g + 2) % 3] + (unsigned)(g + 1);
  }
  *o0 = x0; *o1 = x1;
}

// ---------- 1) stable compaction of idx_train into chosen (y==1) / benign (y==0) ----------
__global__ __launch_bounds__(1024) void k_compact(
    const int* __restrict__ idx_train, const int* __restrict__ y, int NT,
    int* __restrict__ chosen, int* __restrict__ benign) {
  __shared__ int wsum1[16], wsum0[16], woff1[16], woff0[16];
  int t = threadIdx.x;
  int lane = t & 63, w = t >> 6;
  int ept = (NT + 1023) >> 10;
  int base = t * ept;
  int n1 = 0, n0 = 0;
  for (int k = 0; k < ept; ++k) {
    int e = base + k;
    if (e < NT) {
      int idx = idx_train[e];
      if (y[idx] == 1) n1++; else n0++;
    }
  }
  int s1 = n1, s0 = n0;
#pragma unroll
  for (int d = 1; d < 64; d <<= 1) {
    int v1 = __shfl_up(s1, d, 64);
    int v0 = __shfl_up(s0, d, 64);
    if (lane >= d) { s1 += v1; s0 += v0; }
  }
  if (lane == 63) { wsum1[w] = s1; wsum0[w] = s0; }
  __syncthreads();
  if (t == 0) {
    int a = 0, b = 0;
    for (int i = 0; i < 16; ++i) {
      woff1[i] = a; a += wsum1[i];
      woff0[i] = b; b += wsum0[i];
    }
  }
  __syncthreads();
  int p1 = woff1[w] + s1 - n1;
  int p0 = woff0[w] + s0 - n0;
  for (int k = 0; k < ept; ++k) {
    int e = base + k;
    if (e < NT) {
      int idx = idx_train[e];
      if (y[idx] == 1) chosen[p1++] = idx; else benign[p0++] = idx;
    }
  }
}

// ---------- 2) threefry sampling: brow[j] = benign[randint_j] ----------
__global__ void k_sample(const int* __restrict__ benign, int n, unsigned span,
                         unsigned k1a, unsigned k1b, unsigned k2a, unsigned k2b,
                         unsigned mult, int* __restrict__ brow) {
  int j = blockIdx.x * blockDim.x + threadIdx.x;
  if (j >= n) return;
  unsigned a0, a1, b0, b1;
  tf2x32(k1a, k1b, 0u, (unsigned)j, &a0, &a1);  // higher bits (partitionable path)
  tf2x32(k2a, k2b, 0u, (unsigned)j, &b0, &b1);  // lower bits
  unsigned hi = a0 ^ a1, lo = b0 ^ b1;
  unsigned r = ((hi % span) * mult + (lo % span)) % span;
  brow[j] = benign[r];
}

// ---------- 3) squared norms of gathered rows ----------
__global__ __launch_bounds__(64) void k_norms(
    const float* __restrict__ x, const int* __restrict__ crow,
    const int* __restrict__ brow, int n, float* __restrict__ normc,
    float* __restrict__ normb) {
  int b = blockIdx.x;
  int lane = threadIdx.x;
  bool isC = (b < n);
  int j = isC ? b : (b - n);
  int row = isC ? crow[j] : brow[j];
  float4 v = ((const float4*)(x + (size_t)row * Dims))[lane];
  float s = v.x * v.x + v.y * v.y + v.z * v.z + v.w * v.w;
#pragma unroll
  for (int m = 32; m >= 1; m >>= 1) s += __shfl_xor(s, m, 64);
  if (lane == 0) { if (isC) normc[j] = s; else normb[j] = s; }
}

// ---------- 4) tiled distance + fused per-row argmin (no n^2 matrix) ----------
__global__ __launch_bounds__(256) void k_dist(
    const float* __restrict__ x, const int* __restrict__ crow,
    const int* __restrict__ brow, const float* __restrict__ normc,
    const float* __restrict__ normb, int n, int* __restrict__ neigh) {
  __shared__ float cs[BM][Dims + 4];
  __shared__ float bs[BN][KC + 4];
  const int tid = threadIdx.x;
  const int tx = tid & 15, ty = tid >> 4;
  const int R0 = blockIdx.x * BM;
  const int gra = R0 + ty, grb = R0 + ty + 16;

  for (int k = tid; k < BM * (Dims / 4); k += 256) {
    int r = k >> 6, i4 = k & 63;
    int gr = R0 + r;
    float4 v = make_float4(0.f, 0.f, 0.f, 0.f);
    if (gr < n) v = *(const float4*)(x + (size_t)crow[gr] * Dims + i4 * 4);
    *(float4*)(&cs[r][i4 * 4]) = v;
  }

  float nca = 0.f, ncb = 0.f;
  if (gra < n) nca = normc[gra];
  if (grb < n) ncb = normc[grb];

  float bva = 3.4e38f, bvb = 3.4e38f;
  int bia = 0, bib = 0;

  for (int C0 = 0; C0 < n; C0 += BN) {
    float a00 = 0.f, a01 = 0.f, a10 = 0.f, a11 = 0.f;
    for (int k0 = 0; k0 < Dims; k0 += KC) {
      __syncthreads();
      for (int k = tid; k < BN * (KC / 4); k += 256) {
        int c = k >> 5, i4 = k & 31;
        int gc = C0 + c;
        float4 v = make_float4(0.f, 0.f, 0.f, 0.f);
        if (gc < n) v = *(const float4*)(x + (size_t)brow[gc] * Dims + k0 + i4 * 4);
        *(float4*)(&bs[c][i4 * 4]) = v;
      }
      __syncthreads();
#pragma unroll 8
      for (int i = 0; i < KC; i += 4) {
        float4 ca = *(const float4*)(&cs[ty][k0 + i]);
        float4 cb = *(const float4*)(&cs[ty + 16][k0 + i]);
        float4 ba = *(const float4*)(&bs[tx][i]);
        float4 bb = *(const float4*)(&bs[tx + 16][i]);
        a00 += ca.x * ba.x + ca.y * ba.y + ca.z * ba.z + ca.w * ba.w;
        a01 += ca.x * bb.x + ca.y * bb.y + ca.z * bb.z + ca.w * bb.w;
        a10 += cb.x * ba.x + cb.y * ba.y + cb.z * ba.z + cb.w * ba.w;
        a11 += cb.x * bb.x + cb.y * bb.y + cb.z * bb.z + cb.w * bb.w;
      }
    }
    int gca = C0 + tx, gcb = C0 + tx + 16;
    if (gca < n) {
      float nbv = normb[gca];
      if (gra < n && gca != gra) {
        float d2 = nca + nbv - 2.f * a00;
        if (d2 < bva) { bva = d2; bia = gca; }
      }
      if (grb < n && gca != grb) {
        float d2 = ncb + nbv - 2.f * a10;
        if (d2 < bvb) { bvb = d2; bib = gca; }
      }
    }
    if (gcb < n) {
      float nbv = normb[gcb];
      if (gra < n && gcb != gra) {
        float d2 = nca + nbv - 2.f * a01;
        if (d2 < bva) { bva = d2; bia = gcb; }
      }
      if (grb < n && gcb != grb) {
        float d2 = ncb + nbv - 2.f * a11;
        if (d2 < bvb) { bvb = d2; bib = gcb; }
      }
    }
  }
#pragma unroll
  for (int m = 1; m < 16; m <<= 1) {
    float ov = __shfl_xor(bva, m, 64);
    int   oi = __shfl_xor(bia, m, 64);
    if (ov < bva || (ov == bva && oi < bia)) { bva = ov; bia = oi; }
    ov = __shfl_xor(bvb, m, 64);
    oi = __shfl_xor(bib, m, 64);
    if (ov < bvb || (ov == bvb && oi < bib)) { bvb = ov; bib = oi; }
  }
  if (tx == 0) {
    if (gra < n) neigh[gra] = bia;
    if (grb < n) neigh[grb] = bib;
  }
}

// ---------- 5) interpolated synthetic rows ----------
__global__ __launch_bounds__(64) void k_newembed(
    const float* __restrict__ x, const int* __restrict__ crow,
    const int* __restrict__ brow, const int* __restrict__ neigh,
    int N, float interp, float* __restrict__ out) {
  int r = blockIdx.x;
  int lane = threadIdx.x;
  const float4* c = (const float4*)(x + (size_t)crow[r] * Dims);
  const float4* b = (const float4*)(x + (size_t)brow[neigh[r]] * Dims);
  float4 cv = c[lane], bv = b[lane];
  float4 o;
  o.x = cv.x + (bv.x - cv.x) * interp;
  o.y = cv.y + (bv.y - cv.y) * interp;
  o.z = cv.z + (bv.z - cv.z) * interp;
  o.w = cv.w + (bv.w - cv.w) * interp;
  ((float4*)(out + ((size_t)N + r) * Dims))[lane] = o;
}

// ---------- 6) y_out and idx_out tails ----------
__global__ void k_tail(const int* __restrict__ y, const int* __restrict__ idx_train,
                       int N, int NT, int n, float* __restrict__ out) {
  long base2 = (long)(N + n) * Dims;
  long base3 = base2 + (N + n);
  int stride = gridDim.x * blockDim.x;
  for (int k = blockIdx.x * blockDim.x + threadIdx.x; k < N + n; k += stride)
    out[base2 + k] = (k < N) ? (float)y[k] : 1.0f;
  for (int k = blockIdx.x * blockDim.x + threadIdx.x; k < NT + n; k += stride)
    out[base3 + k] = (k < NT) ? (float)idx_train[k] : (float)(N + (k - NT));
}

extern "C" void kernel_launch(void* const* d_in, const int* in_sizes, int n_in,
                              void* d_out, int out_size, void* d_ws, size_t ws_size,
                              hipStream_t stream) {
  const float* x = (const float*)d_in[0];
  const int* y = (const int*)d_in[1];
  const int* idx_train = (const int*)d_in[2];
  float* out = (float*)d_out;
  const int N = in_sizes[1];
  const int NT = in_sizes[2];

  // out_size = 257*N + NT + 258*n  ->  n (minority count) host-side
  long nl = ((long)out_size - ((long)N * Dims + N + NT)) / (Dims + 2);
  int n = (int)nl;
  if (n < 0) n = 0;
  if (n > NT) n = NT;
  int nb = NT - n;

  // workspace layout (ints/floats, each segment NT-capacity, 1KB-aligned)
  size_t cap = ((size_t)NT + 255) & ~(size_t)255;
  int* chosen = (int*)d_ws;
  int* benign = chosen + cap;
  int* brow = benign + cap;
  int* neigh = brow + cap;
  float* normc = (float*)(neigh + cap);
  float* normb = normc + cap;

  // Host-side JAX threefry derivations from key(42) (partitionable path):
  // split -> k_samp = tf(key,0,0), k_interp = tf(key,0,1)
  unsigned s0_, s1_, t0_, t1_;
  tf2x32(0u, 42u, 0u, 0u, &s0_, &s1_);
  tf2x32(0u, 42u, 0u, 1u, &t0_, &t1_);
  // interp_place = uniform(k_interp)
  unsigned i0_, i1_;
  tf2x32(t0_, t1_, 0u, 0u, &i0_, &i1_);
  unsigned ub = i0_ ^ i1_;
  float interp;
  { unsigned uu = (ub >> 9) | 0x3f800000u; memcpy(&interp, &uu, 4); interp -= 1.0f; }
  // randint internal split of k_samp -> k1 (higher bits), k2 (lower bits)
  unsigned k1a, k1b, k2a, k2b;
  { unsigned a, b; tf2x32(s0_, s1_, 0u, 0u, &a, &b); k1a = a; k1b = b; }
  { unsigned a, b; tf2x32(s0_, s1_, 0u, 1u, &a, &b); k2a = a; k2b = b; }
  unsigned span = (nb > 0) ? (unsigned)nb : 1u;
  unsigned m0 = 65536u % span;
  unsigned mult = (m0 * m0) % span;  // (2^32 mod span), computed as JAX does

  k_compact<<<1, 1024, 0, stream>>>(idx_train, y, NT, chosen, benign);
  if (n > 0 && nb > 0) {
    k_sample<<<(n + 255) / 256, 256, 0, stream>>>(benign, n, span, k1a, k1b, k2a, k2b, mult, brow);
    k_norms<<<2 * n, 64, 0, stream>>>(x, chosen, brow, n, normc, normb);
    k_dist<<<(n + BM - 1) / BM, 256, 0, stream>>>(x, chosen, brow, normc, normb, n, neigh);
  }
  hipMemcpyAsync(out, x, (size_t)N * Dims * sizeof(float), hipMemcpyDeviceToDevice, stream);
  if (n > 0 && nb > 0)
    k_newembed<<<n, 64, 0, stream>>>(x, chosen, brow, neigh, N, interp, out);
  k_tail<<<512, 256, 0, stream>>>(y, idx_train, N, NT, n, out);
}

// Round 2
// 388.670 us; speedup vs baseline: 11.8264x; 11.8264x over previous
//
#include <hip/hip_runtime.h>
#include <string.h>

#define Dims 256
#define BM 32
#define BN 32
#define KC 128
#define NSEG 8

typedef short bf16x8 __attribute__((ext_vector_type(8)));
typedef float f32x4 __attribute__((ext_vector_type(4)));

// ---------- Threefry2x32 (JAX), usable host+device ----------
__host__ __device__ inline void tf2x32(unsigned k0, unsigned k1,
                                       unsigned x0, unsigned x1,
                                       unsigned* o0, unsigned* o1) {
  unsigned ks[3] = {k0, k1, k0 ^ k1 ^ 0x1BD11BDAu};
  x0 += ks[0]; x1 += ks[1];
  const unsigned rA[4] = {13u, 15u, 26u, 6u};
  const unsigned rB[4] = {17u, 29u, 16u, 24u};
#pragma unroll
  for (int g = 0; g < 5; ++g) {
    const unsigned* rr = (g & 1) ? rB : rA;
#pragma unroll
    for (int j = 0; j < 4; ++j) {
      x0 += x1;
      x1 = (x1 << rr[j]) | (x1 >> (32u - rr[j]));
      x1 ^= x0;
    }
    x0 += ks[(g + 1) % 3];
    x1 += ks[(g + 2) % 3] + (unsigned)(g + 1);
  }
  *o0 = x0; *o1 = x1;
}

__device__ inline unsigned short f2bf(float f) {
  unsigned u = __builtin_bit_cast(unsigned, f);
  unsigned r = (u + 0x7fffu + ((u >> 16) & 1u)) >> 16;
  return (unsigned short)r;
}

// ---------- 1) stable compaction of idx_train into chosen (y==1) / benign (y==0) ----------
__global__ __launch_bounds__(1024) void k_compact(
    const int* __restrict__ idx_train, const int* __restrict__ y, int NT,
    int* __restrict__ chosen, int* __restrict__ benign) {
  __shared__ int wsum1[16], wsum0[16], woff1[16], woff0[16];
  int t = threadIdx.x;
  int lane = t & 63, w = t >> 6;
  int ept = (NT + 1023) >> 10;
  int base = t * ept;
  int n1 = 0, n0 = 0;
  for (int k = 0; k < ept; ++k) {
    int e = base + k;
    if (e < NT) {
      int idx = idx_train[e];
      if (y[idx] == 1) n1++; else n0++;
    }
  }
  int s1 = n1, s0 = n0;
#pragma unroll
  for (int d = 1; d < 64; d <<= 1) {
    int v1 = __shfl_up(s1, d, 64);
    int v0 = __shfl_up(s0, d, 64);
    if (lane >= d) { s1 += v1; s0 += v0; }
  }
  if (lane == 63) { wsum1[w] = s1; wsum0[w] = s0; }
  __syncthreads();
  if (t == 0) {
    int a = 0, b = 0;
    for (int i = 0; i < 16; ++i) {
      woff1[i] = a; a += wsum1[i];
      woff0[i] = b; b += wsum0[i];
    }
  }
  __syncthreads();
  int p1 = woff1[w] + s1 - n1;
  int p0 = woff0[w] + s0 - n0;
  for (int k = 0; k < ept; ++k) {
    int e = base + k;
    if (e < NT) {
      int idx = idx_train[e];
      if (y[idx] == 1) chosen[p1++] = idx; else benign[p0++] = idx;
    }
  }
}

// ---------- 2) threefry sampling: brow[j] = benign[randint_j] ----------
__global__ void k_sample(const int* __restrict__ benign, int n, unsigned span,
                         unsigned k1a, unsigned k1b, unsigned k2a, unsigned k2b,
                         unsigned mult, int* __restrict__ brow) {
  int j = blockIdx.x * blockDim.x + threadIdx.x;
  if (j >= n) return;
  unsigned a0, a1, b0, b1;
  tf2x32(k1a, k1b, 0u, (unsigned)j, &a0, &a1);
  tf2x32(k2a, k2b, 0u, (unsigned)j, &b0, &b1);
  unsigned hi = a0 ^ a1, lo = b0 ^ b1;
  unsigned r = ((hi % span) * mult + (lo % span)) % span;
  brow[j] = benign[r];
}

// ---------- 3) gather + fp32->bf16 convert into packed panels (padded to ncap) ----------
__global__ __launch_bounds__(64) void k_convert(
    const float* __restrict__ x, const int* __restrict__ crow,
    const int* __restrict__ brow, int n, int ncap,
    unsigned short* __restrict__ Cb, unsigned short* __restrict__ Bb) {
  int b = blockIdx.x;
  int lane = threadIdx.x;
  bool isC = (b < ncap);
  int j = isC ? b : (b - ncap);
  unsigned short* dst = (isC ? Cb : Bb) + ((size_t)j << 8) + lane * 4;
  ushort4 o = {0, 0, 0, 0};
  if (j < n) {
    int row = isC ? crow[j] : brow[j];
    float4 v = ((const float4*)(x + ((size_t)row << 8)))[lane];
    o.x = f2bf(v.x); o.y = f2bf(v.y); o.z = f2bf(v.z); o.w = f2bf(v.w);
  }
  *(ushort4*)dst = o;
}

// ---------- 4) squared norms (fp32), padded: normb[pad]=3.4e38 ----------
__global__ __launch_bounds__(64) void k_norms(
    const float* __restrict__ x, const int* __restrict__ crow,
    const int* __restrict__ brow, int n, int ncap, float* __restrict__ normc,
    float* __restrict__ normb) {
  int b = blockIdx.x;
  int lane = threadIdx.x;
  bool isC = (b < ncap);
  int j = isC ? b : (b - ncap);
  if (j >= n) {
    if (lane == 0) { if (isC) normc[j] = 0.f; else normb[j] = 3.4e38f; }
    return;
  }
  int row = isC ? crow[j] : brow[j];
  float4 v = ((const float4*)(x + ((size_t)row << 8)))[lane];
  float s = v.x * v.x + v.y * v.y + v.z * v.z + v.w * v.w;
#pragma unroll
  for (int m = 32; m >= 1; m >>= 1) s += __shfl_xor(s, m, 64);
  if (lane == 0) { if (isC) normc[j] = s; else normb[j] = s; }
}

// ---------- 5) init packed argmin keys ----------
__global__ void k_init(unsigned long long* __restrict__ packed, int ncap) {
  int i = blockIdx.x * blockDim.x + threadIdx.x;
  if (i < ncap) packed[i] = ~0ULL;
}

// ---------- 6) MFMA distance + fused argmin ----------
__global__ __launch_bounds__(256, 2) void k_mdist(
    const unsigned short* __restrict__ Cb, const unsigned short* __restrict__ Bb,
    const float* __restrict__ normc, const float* __restrict__ normb,
    int n, int ncap, unsigned long long* __restrict__ packed) {
  __shared__ __align__(16) unsigned short As[128 * 256];  // 64KB, swizzled 16B slots
  __shared__ __align__(16) unsigned short Bs[128 * 64];   // 16KB, swizzled
  const int tid = threadIdx.x;
  const int lane = tid & 63;
  const int wid = tid >> 6;
  const int wm = wid >> 1, wn = wid & 1;
  const int R0 = blockIdx.x * 128;
  const int ntiles = ncap >> 7;
  const int per = (ntiles + NSEG - 1) / NSEG;
  int t0 = blockIdx.y * per;
  int t1 = t0 + per; if (t1 > ntiles) t1 = ntiles;
  if (t0 >= t1) return;

  // stage A panel once: rows R0..R0+127, all 256 k. slot-swizzle: slot ^= (row&7)
#pragma unroll
  for (int p = 0; p < 16; ++p) {
    int u = p * 256 + tid;
    int r = u >> 5, c = u & 31;
    uint4 v = *(const uint4*)(Cb + ((size_t)(R0 + r) << 8) + c * 8);
    *(uint4*)((char*)As + r * 512 + (((c ^ (r & 7))) << 4)) = v;
  }

  const int lr = lane & 15, lg = lane >> 4;

  float nc[4][4];
#pragma unroll
  for (int mf = 0; mf < 4; ++mf)
#pragma unroll
    for (int j = 0; j < 4; ++j)
      nc[mf][j] = normc[R0 + wm * 64 + mf * 16 + lg * 4 + j];

  float bval[4][4];
  int bcol[4][4];
#pragma unroll
  for (int mf = 0; mf < 4; ++mf)
#pragma unroll
    for (int j = 0; j < 4; ++j) { bval[mf][j] = __builtin_inff(); bcol[mf][j] = 0; }

  for (int ct = t0; ct < t1; ++ct) {
    const int C0 = ct << 7;
    f32x4 acc[4][4];
#pragma unroll
    for (int mf = 0; mf < 4; ++mf)
#pragma unroll
      for (int nf = 0; nf < 4; ++nf) acc[mf][nf] = (f32x4){0.f, 0.f, 0.f, 0.f};

#pragma unroll
    for (int k0 = 0; k0 < 256; k0 += 64) {
      __syncthreads();
#pragma unroll
      for (int p = 0; p < 4; ++p) {
        int u = p * 256 + tid;
        int r = u >> 3, c = u & 7;
        uint4 v = *(const uint4*)(Bb + ((size_t)(C0 + r) << 8) + k0 + c * 8);
        *(uint4*)((char*)Bs + r * 128 + ((c ^ (r & 7)) << 4)) = v;
      }
      __syncthreads();
#pragma unroll
      for (int ks = 0; ks < 2; ++ks) {
        bf16x8 af[4], bg[4];
#pragma unroll
        for (int mf = 0; mf < 4; ++mf) {
          int r = wm * 64 + mf * 16 + lr;
          int slot = (k0 >> 3) + ks * 4 + lg;
          af[mf] = *(const bf16x8*)((const char*)As + r * 512 + ((slot ^ (r & 7)) << 4));
        }
#pragma unroll
        for (int nf = 0; nf < 4; ++nf) {
          int r = wn * 64 + nf * 16 + lr;
          int slot = ks * 4 + lg;
          bg[nf] = *(const bf16x8*)((const char*)Bs + r * 128 + ((slot ^ (r & 7)) << 4));
        }
#pragma unroll
        for (int mf = 0; mf < 4; ++mf)
#pragma unroll
          for (int nf = 0; nf < 4; ++nf)
            acc[mf][nf] = __builtin_amdgcn_mfma_f32_16x16x32_bf16(af[mf], bg[nf], acc[mf][nf], 0, 0, 0);
      }
    }
    // fused epilogue: d2 + diagonal mask + running argmin
    float nb[4]; int colg[4];
#pragma unroll
    for (int nf = 0; nf < 4; ++nf) {
      colg[nf] = C0 + wn * 64 + nf * 16 + lr;
      nb[nf] = normb[colg[nf]];
    }
#pragma unroll
    for (int mf = 0; mf < 4; ++mf) {
#pragma unroll
      for (int j = 0; j < 4; ++j) {
        int rowg = R0 + wm * 64 + mf * 16 + lg * 4 + j;
        float base = nc[mf][j];
#pragma unroll
        for (int nf = 0; nf < 4; ++nf) {
          float d2 = base + nb[nf] - 2.0f * acc[mf][nf][j];
          d2 = fmaxf(d2, 0.0f);
          if ((colg[nf] != rowg) && (d2 < bval[mf][j])) {
            bval[mf][j] = d2;
            bcol[mf][j] = colg[nf];
          }
        }
      }
    }
  }
  // cross-lane reduce (16 lanes share each row-group) + global combine
#pragma unroll
  for (int mf = 0; mf < 4; ++mf) {
#pragma unroll
    for (int j = 0; j < 4; ++j) {
      unsigned long long pk =
          ((unsigned long long)__builtin_bit_cast(unsigned, bval[mf][j]) << 32) |
          (unsigned)bcol[mf][j];
#pragma unroll
      for (int m = 1; m < 16; m <<= 1) {
        unsigned long long o = __shfl_xor(pk, m, 64);
        if (o < pk) pk = o;
      }
      if (lr == 0) {
        int rowg = R0 + wm * 64 + mf * 16 + lg * 4 + j;
        if (rowg < n) atomicMin(&packed[rowg], pk);
      }
    }
  }
}

// ---------- fallback fp32 distance (ws too small) ----------
__global__ __launch_bounds__(256) void k_dist(
    const float* __restrict__ x, const int* __restrict__ crow,
    const int* __restrict__ brow, const float* __restrict__ normc,
    const float* __restrict__ normb, int n, int* __restrict__ neigh) {
  __shared__ float cs[BM][Dims + 4];
  __shared__ float bs[BN][KC + 4];
  const int tid = threadIdx.x;
  const int tx = tid & 15, ty = tid >> 4;
  const int R0 = blockIdx.x * BM;
  const int gra = R0 + ty, grb = R0 + ty + 16;
  for (int k = tid; k < BM * (Dims / 4); k += 256) {
    int r = k >> 6, i4 = k & 63;
    int gr = R0 + r;
    float4 v = make_float4(0.f, 0.f, 0.f, 0.f);
    if (gr < n) v = *(const float4*)(x + (size_t)crow[gr] * Dims + i4 * 4);
    *(float4*)(&cs[r][i4 * 4]) = v;
  }
  float nca = 0.f, ncb = 0.f;
  if (gra < n) nca = normc[gra];
  if (grb < n) ncb = normc[grb];
  float bva = 3.4e38f, bvb = 3.4e38f;
  int bia = 0, bib = 0;
  for (int C0 = 0; C0 < n; C0 += BN) {
    float a00 = 0.f, a01 = 0.f, a10 = 0.f, a11 = 0.f;
    for (int k0 = 0; k0 < Dims; k0 += KC) {
      __syncthreads();
      for (int k = tid; k < BN * (KC / 4); k += 256) {
        int c = k >> 5, i4 = k & 31;
        int gc = C0 + c;
        float4 v = make_float4(0.f, 0.f, 0.f, 0.f);
        if (gc < n) v = *(const float4*)(x + (size_t)brow[gc] * Dims + k0 + i4 * 4);
        *(float4*)(&bs[c][i4 * 4]) = v;
      }
      __syncthreads();
#pragma unroll 8
      for (int i = 0; i < KC; i += 4) {
        float4 ca = *(const float4*)(&cs[ty][k0 + i]);
        float4 cb = *(const float4*)(&cs[ty + 16][k0 + i]);
        float4 ba = *(const float4*)(&bs[tx][i]);
        float4 bb = *(const float4*)(&bs[tx + 16][i]);
        a00 += ca.x * ba.x + ca.y * ba.y + ca.z * ba.z + ca.w * ba.w;
        a01 += ca.x * bb.x + ca.y * bb.y + ca.z * bb.z + ca.w * bb.w;
        a10 += cb.x * ba.x + cb.y * ba.y + cb.z * ba.z + cb.w * ba.w;
        a11 += cb.x * bb.x + cb.y * bb.y + cb.z * bb.z + cb.w * bb.w;
      }
    }
    int gca = C0 + tx, gcb = C0 + tx + 16;
    if (gca < n) {
      float nbv = normb[gca];
      if (gra < n && gca != gra) {
        float d2 = nca + nbv - 2.f * a00;
        if (d2 < bva) { bva = d2; bia = gca; }
      }
      if (grb < n && gca != grb) {
        float d2 = ncb + nbv - 2.f * a10;
        if (d2 < bvb) { bvb = d2; bib = gca; }
      }
    }
    if (gcb < n) {
      float nbv = normb[gcb];
      if (gra < n && gcb != gra) {
        float d2 = nca + nbv - 2.f * a01;
        if (d2 < bva) { bva = d2; bia = gcb; }
      }
      if (grb < n && gcb != grb) {
        float d2 = ncb + nbv - 2.f * a11;
        if (d2 < bvb) { bvb = d2; bib = gcb; }
      }
    }
  }
#pragma unroll
  for (int m = 1; m < 16; m <<= 1) {
    float ov = __shfl_xor(bva, m, 64);
    int oi = __shfl_xor(bia, m, 64);
    if (ov < bva || (ov == bva && oi < bia)) { bva = ov; bia = oi; }
    ov = __shfl_xor(bvb, m, 64);
    oi = __shfl_xor(bib, m, 64);
    if (ov < bvb || (ov == bvb && oi < bib)) { bvb = ov; bib = oi; }
  }
  if (tx == 0) {
    if (gra < n) neigh[gra] = bia;
    if (grb < n) neigh[grb] = bib;
  }
}

// ---------- 7) interpolated synthetic rows ----------
__global__ __launch_bounds__(64) void k_newembed_packed(
    const float* __restrict__ x, const int* __restrict__ crow,
    const int* __restrict__ brow, const unsigned long long* __restrict__ packed,
    int N, float interp, float* __restrict__ out) {
  int r = blockIdx.x;
  int lane = threadIdx.x;
  unsigned long long pk = packed[r];
  int col = (pk == ~0ULL) ? 0 : (int)(unsigned)(pk & 0xffffffffULL);
  const float4* c = (const float4*)(x + (size_t)crow[r] * Dims);
  const float4* b = (const float4*)(x + (size_t)brow[col] * Dims);
  float4 cv = c[lane], bv = b[lane];
  float4 o;
  o.x = cv.x + (bv.x - cv.x) * interp;
  o.y = cv.y + (bv.y - cv.y) * interp;
  o.z = cv.z + (bv.z - cv.z) * interp;
  o.w = cv.w + (bv.w - cv.w) * interp;
  ((float4*)(out + ((size_t)N + r) * Dims))[lane] = o;
}

__global__ __launch_bounds__(64) void k_newembed_int(
    const float* __restrict__ x, const int* __restrict__ crow,
    const int* __restrict__ brow, const int* __restrict__ neigh,
    int N, float interp, float* __restrict__ out) {
  int r = blockIdx.x;
  int lane = threadIdx.x;
  const float4* c = (const float4*)(x + (size_t)crow[r] * Dims);
  const float4* b = (const float4*)(x + (size_t)brow[neigh[r]] * Dims);
  float4 cv = c[lane], bv = b[lane];
  float4 o;
  o.x = cv.x + (bv.x - cv.x) * interp;
  o.y = cv.y + (bv.y - cv.y) * interp;
  o.z = cv.z + (bv.z - cv.z) * interp;
  o.w = cv.w + (bv.w - cv.w) * interp;
  ((float4*)(out + ((size_t)N + r) * Dims))[lane] = o;
}

// ---------- 8) y_out and idx_out tails ----------
__global__ void k_tail(const int* __restrict__ y, const int* __restrict__ idx_train,
                       int N, int NT, int n, float* __restrict__ out) {
  long base2 = (long)(N + n) * Dims;
  long base3 = base2 + (N + n);
  int stride = gridDim.x * blockDim.x;
  for (int k = blockIdx.x * blockDim.x + threadIdx.x; k < N + n; k += stride)
    out[base2 + k] = (k < N) ? (float)y[k] : 1.0f;
  for (int k = blockIdx.x * blockDim.x + threadIdx.x; k < NT + n; k += stride)
    out[base3 + k] = (k < NT) ? (float)idx_train[k] : (float)(N + (k - NT));
}

extern "C" void kernel_launch(void* const* d_in, const int* in_sizes, int n_in,
                              void* d_out, int out_size, void* d_ws, size_t ws_size,
                              hipStream_t stream) {
  const float* x = (const float*)d_in[0];
  const int* y = (const int*)d_in[1];
  const int* idx_train = (const int*)d_in[2];
  float* out = (float*)d_out;
  const int N = in_sizes[1];
  const int NT = in_sizes[2];

  long nl = ((long)out_size - ((long)N * Dims + N + NT)) / (Dims + 2);
  int n = (int)nl;
  if (n < 0) n = 0;
  if (n > NT) n = NT;
  int nb = NT - n;
  int ncap = (n + 127) & ~127;
  if (ncap < 128) ncap = 128;

  size_t cap = ((size_t)NT + 255) & ~(size_t)255;
  int* chosen = (int*)d_ws;
  int* benign = chosen + cap;
  int* brow = benign + cap;
  int* neigh = brow + cap;
  float* normc = (float*)(neigh + cap);
  float* normb = normc + cap;
  unsigned long long* packed = (unsigned long long*)(normb + cap);
  unsigned short* Cb = (unsigned short*)(packed + ncap);
  unsigned short* Bb = Cb + (size_t)ncap * 256;
  size_t need = (char*)(Bb + (size_t)ncap * 256) - (char*)d_ws;
  bool use_mfma = (ws_size >= need);

  // Host-side JAX threefry derivations from key(42)
  unsigned s0_, s1_, t0_, t1_;
  tf2x32(0u, 42u, 0u, 0u, &s0_, &s1_);
  tf2x32(0u, 42u, 0u, 1u, &t0_, &t1_);
  unsigned i0_, i1_;
  tf2x32(t0_, t1_, 0u, 0u, &i0_, &i1_);
  unsigned ub = i0_ ^ i1_;
  float interp;
  { unsigned uu = (ub >> 9) | 0x3f800000u; memcpy(&interp, &uu, 4); interp -= 1.0f; }
  unsigned k1a, k1b, k2a, k2b;
  { unsigned a, b; tf2x32(s0_, s1_, 0u, 0u, &a, &b); k1a = a; k1b = b; }
  { unsigned a, b; tf2x32(s0_, s1_, 0u, 1u, &a, &b); k2a = a; k2b = b; }
  unsigned span = (nb > 0) ? (unsigned)nb : 1u;
  unsigned m0 = 65536u % span;
  unsigned mult = (m0 * m0) % span;

  k_compact<<<1, 1024, 0, stream>>>(idx_train, y, NT, chosen, benign);
  if (n > 0 && nb > 0) {
    k_sample<<<(n + 255) / 256, 256, 0, stream>>>(benign, n, span, k1a, k1b, k2a, k2b, mult, brow);
    if (use_mfma) {
      k_convert<<<2 * ncap, 64, 0, stream>>>(x, chosen, brow, n, ncap, Cb, Bb);
      k_norms<<<2 * ncap, 64, 0, stream>>>(x, chosen, brow, n, ncap, normc, normb);
      k_init<<<(ncap + 255) / 256, 256, 0, stream>>>(packed, ncap);
      dim3 grid(ncap / 128, NSEG);
      k_mdist<<<grid, 256, 0, stream>>>(Cb, Bb, normc, normb, n, ncap, packed);
    } else {
      k_norms<<<2 * ncap, 64, 0, stream>>>(x, chosen, brow, n, ncap, normc, normb);
      k_dist<<<(n + BM - 1) / BM, 256, 0, stream>>>(x, chosen, brow, normc, normb, n, neigh);
    }
  }
  hipMemcpyAsync(out, x, (size_t)N * Dims * sizeof(float), hipMemcpyDeviceToDevice, stream);
  if (n > 0 && nb > 0) {
    if (use_mfma)
      k_newembed_packed<<<n, 64, 0, stream>>>(x, chosen, brow, packed, N, interp, out);
    else
      k_newembed_int<<<n, 64, 0, stream>>>(x, chosen, brow, neigh, N, interp, out);
  }
  k_tail<<<512, 256, 0, stream>>>(y, idx_train, N, NT, n, out);
}